// Round 3
// baseline (770.133 us; speedup 1.0000x reference)
//
#include <hip/hip_runtime.h>

#define N_NODES 100000
#define F 64
#define C 32
#define KH 3
#define E 1600000
#define NE_TOT (KH * E)          // 4,800,000
#define SCAN_B 1024
#define N_SCAN_BLK ((N_NODES + SCAN_B - 1) / SCAN_B)   // 98

// ---------------------------------------------------------------------------
// K1: y[n, c] = sum_f x[n, f] * W[f, c]   (all fp32)
// ---------------------------------------------------------------------------
__global__ __launch_bounds__(256) void gemm_xw(const float* __restrict__ x,
                                               const float* __restrict__ W,
                                               float* __restrict__ y) {
    __shared__ float Ws[F * C];  // 8 KB
    for (int i = threadIdx.x; i < F * C; i += 256) Ws[i] = W[i];
    __syncthreads();

    const int node = blockIdx.x * 256 + threadIdx.x;
    if (node >= N_NODES) return;

    const float4* xp = (const float4*)(x + (size_t)node * F);
    float acc[C];
#pragma unroll
    for (int c = 0; c < C; c++) acc[c] = 0.f;

#pragma unroll
    for (int i = 0; i < 16; i++) {
        float4 v = xp[i];
        const int f = i * 4;
#pragma unroll
        for (int c = 0; c < C; c++) {
            acc[c] += v.x * Ws[(f + 0) * C + c];
            acc[c] += v.y * Ws[(f + 1) * C + c];
            acc[c] += v.z * Ws[(f + 2) * C + c];
            acc[c] += v.w * Ws[(f + 3) * C + c];
        }
    }

    float4* yo = (float4*)(y + (size_t)node * C);
#pragma unroll
    for (int i = 0; i < 8; i++)
        yo[i] = make_float4(acc[4 * i], acc[4 * i + 1], acc[4 * i + 2], acc[4 * i + 3]);
}

// ---------------------------------------------------------------------------
// K2: histogram of destination rows
// ---------------------------------------------------------------------------
__global__ __launch_bounds__(256) void hist_k(const int* __restrict__ rows,
                                              int* __restrict__ cnt) {
    const int e = blockIdx.x * 256 + threadIdx.x;
    if (e >= NE_TOT) return;
    atomicAdd(&cnt[rows[e]], 1);
}

// ---------------------------------------------------------------------------
// K3a/b/c: exclusive scan of cnt[N] -> row_start[N+1]; cursor[i] = row_start[i]
// ---------------------------------------------------------------------------
__global__ __launch_bounds__(SCAN_B) void scan_a(const int* __restrict__ cnt,
                                                 int* __restrict__ row_start,
                                                 int* __restrict__ bsum) {
    __shared__ int s[SCAN_B];
    const int t = threadIdx.x;
    const int i = blockIdx.x * SCAN_B + t;
    s[t] = (i < N_NODES) ? cnt[i] : 0;
    __syncthreads();
    for (int off = 1; off < SCAN_B; off <<= 1) {
        int v = s[t];
        int add = (t >= off) ? s[t - off] : 0;
        __syncthreads();
        s[t] = v + add;
        __syncthreads();
    }
    if (i < N_NODES) row_start[i + 1] = s[t];   // inclusive, block-local
    if (t == SCAN_B - 1) bsum[blockIdx.x] = s[t];
    if (i == 0) row_start[0] = 0;
}

__global__ __launch_bounds__(128) void scan_b(const int* __restrict__ bsum,
                                              int* __restrict__ boff) {
    __shared__ int s[128];
    const int t = threadIdx.x;
    s[t] = (t < N_SCAN_BLK) ? bsum[t] : 0;
    __syncthreads();
    for (int off = 1; off < 128; off <<= 1) {
        int v = s[t];
        int add = (t >= off) ? s[t - off] : 0;
        __syncthreads();
        s[t] = v + add;
        __syncthreads();
    }
    boff[t] = (t >= 1) ? s[t - 1] : 0;          // exclusive
}

__global__ __launch_bounds__(SCAN_B) void scan_c(const int* __restrict__ cnt,
                                                 int* __restrict__ row_start,
                                                 const int* __restrict__ boff,
                                                 int* __restrict__ cursor) {
    const int i = blockIdx.x * SCAN_B + threadIdx.x;
    if (i >= N_NODES) return;
    const int incl = row_start[i + 1] + boff[blockIdx.x];
    row_start[i + 1] = incl;
    cursor[i] = incl - cnt[i];                  // exclusive start of row i
}

// ---------------------------------------------------------------------------
// K4: fill CSR — counting-sort edges by destination row
// ---------------------------------------------------------------------------
__global__ __launch_bounds__(256) void fill_k(
    const float* __restrict__ vals, const int* __restrict__ rows,
    const int* __restrict__ cols, const float* __restrict__ alpha,
    int* __restrict__ cursor, int2* __restrict__ csr) {
    const int e = blockIdx.x * 256 + threadIdx.x;
    if (e >= NE_TOT) return;
    const int k = (e >= 2 * E) ? 2 : (e >= E) ? 1 : 0;
    const float w = vals[e] * alpha[k];
    const int row = rows[e];
    const int col = cols[e];
    const int slot = atomicAdd(&cursor[row], 1);
    csr[slot] = make_int2(col, __float_as_int(w));
}

// ---------------------------------------------------------------------------
// K5: pull — 32 lanes per node (one per channel), atomic-free accumulate
// ---------------------------------------------------------------------------
__global__ __launch_bounds__(256) void pull_k(
    const int* __restrict__ row_start, const int2* __restrict__ csr,
    const float* __restrict__ y, const float* __restrict__ bias,
    float* __restrict__ out) {
    const int node = blockIdx.x * 8 + (threadIdx.x >> 5);
    const int c = threadIdx.x & 31;
    if (node >= N_NODES) return;

    const int start = row_start[node];
    const int end = row_start[node + 1];

    float acc = 0.f;
    int i = start;
    for (; i + 4 <= end; i += 4) {
        const int2 e0 = csr[i + 0];
        const int2 e1 = csr[i + 1];
        const int2 e2 = csr[i + 2];
        const int2 e3 = csr[i + 3];
        const float p0 = y[(size_t)e0.x * C + c];
        const float p1 = y[(size_t)e1.x * C + c];
        const float p2 = y[(size_t)e2.x * C + c];
        const float p3 = y[(size_t)e3.x * C + c];
        acc += __int_as_float(e0.y) * p0;
        acc += __int_as_float(e1.y) * p1;
        acc += __int_as_float(e2.y) * p2;
        acc += __int_as_float(e3.y) * p3;
    }
    for (; i < end; i++) {
        const int2 e0 = csr[i];
        acc += __int_as_float(e0.y) * y[(size_t)e0.x * C + c];
    }
    out[(size_t)node * C + c] = acc + bias[c];
}

// ---------------------------------------------------------------------------
extern "C" void kernel_launch(void* const* d_in, const int* in_sizes, int n_in,
                              void* d_out, int out_size, void* d_ws, size_t ws_size,
                              hipStream_t stream) {
    const float* x         = (const float*)d_in[0];
    const float* edge_vals = (const float*)d_in[1];
    const float* W         = (const float*)d_in[2];
    const float* b         = (const float*)d_in[3];
    const float* alpha     = (const float*)d_in[4];
    const int*   edge_rows = (const int*)d_in[5];
    const int*   edge_cols = (const int*)d_in[6];
    float*       out       = (float*)d_out;          // [N, C] fp32

    // ws layout (int/float units, 4 B each)
    int* wsi = (int*)d_ws;
    float* y        = (float*)wsi;                    // 3,200,000 f32 (12.8 MB)
    int*   cnt      = wsi + 3200000;                  // N
    int*   row_st   = wsi + 3300000;                  // N+1
    int*   cursor   = wsi + 3400002;                  // N   (offset padded even)
    int*   bsum     = wsi + 3500002;                  // 128
    int*   boff     = wsi + 3500130;                  // 128
    int2*  csr      = (int2*)(wsi + 3500258);         // 4.8M int2 (38.4 MB), 8B-aligned

    hipMemsetAsync(cnt, 0, N_NODES * sizeof(int), stream);

    gemm_xw<<<(N_NODES + 255) / 256, 256, 0, stream>>>(x, W, y);

    hist_k<<<(NE_TOT + 255) / 256, 256, 0, stream>>>(edge_rows, cnt);

    scan_a<<<N_SCAN_BLK, SCAN_B, 0, stream>>>(cnt, row_st, bsum);
    scan_b<<<1, 128, 0, stream>>>(bsum, boff);
    scan_c<<<N_SCAN_BLK, SCAN_B, 0, stream>>>(cnt, row_st, boff, cursor);

    fill_k<<<(NE_TOT + 255) / 256, 256, 0, stream>>>(
        edge_vals, edge_rows, edge_cols, alpha, cursor, csr);

    pull_k<<<(N_NODES + 7) / 8, 256, 0, stream>>>(row_st, csr, y, b, out);
}